// Round 6
// baseline (4139.962 us; speedup 1.0000x reference)
//
#include <hip/hip_runtime.h>

#define L_DIM 1024
#define B_DIM 128
#define I_DIM 256
#define H_DIM 512

typedef unsigned short u16x8 __attribute__((ext_vector_type(8)));
typedef __bf16 bf16x8 __attribute__((ext_vector_type(8)));
typedef float f32x4 __attribute__((ext_vector_type(4)));
typedef unsigned long long u64;
typedef unsigned int u32;

static __device__ __forceinline__ unsigned short f2bf(float f) {
  unsigned u = __builtin_bit_cast(unsigned, f);
  u += 0x7FFFu + ((u >> 16) & 1u);
  return (unsigned short)(u >> 16);
}
static __device__ __forceinline__ float bf2f(unsigned short b) {
  return __builtin_bit_cast(float, ((unsigned)b) << 16);
}
static __device__ __forceinline__ bf16x8 ld_frag_g(const unsigned short* p, size_t idx8) {
  return __builtin_bit_cast(bf16x8, reinterpret_cast<const u16x8*>(p)[idx8]);
}

// ---------------------------------------------------------------------------
// Pack Wx and Wh into MFMA B-fragment order, split hi/lo bf16. (unchanged)
// B-frag: lane l holds B[k = kt*32+(l>>4)*8+j][n = nt*16+(l&15)], W stored [n][k].
// ---------------------------------------------------------------------------
__global__ void pack_weights(const float* __restrict__ Wx, const float* __restrict__ Wh,
                             unsigned short* __restrict__ WxHi, unsigned short* __restrict__ WxLo,
                             unsigned short* __restrict__ WhHi, unsigned short* __restrict__ WhLo) {
  int tid = blockIdx.x * blockDim.x + threadIdx.x;
  if (tid < 32 * 8 * 64) {
    int lane = tid & 63, kt = (tid >> 6) & 7, nt = tid >> 9;
    int n = nt * 16 + (lane & 15), k0 = kt * 32 + (lane >> 4) * 8;
    const float* src = Wx + (size_t)n * I_DIM + k0;
    #pragma unroll
    for (int j = 0; j < 8; ++j) {
      float v = src[j];
      unsigned short hb = f2bf(v);
      WxHi[(size_t)tid * 8 + j] = hb;
      WxLo[(size_t)tid * 8 + j] = f2bf(v - bf2f(hb));
    }
  }
  if (tid < 32 * 16 * 64) {
    int lane = tid & 63, kt = (tid >> 6) & 15, nt = tid >> 10;
    int n = nt * 16 + (lane & 15), k0 = kt * 32 + (lane >> 4) * 8;
    const float* src = Wh + (size_t)n * H_DIM + k0;
    #pragma unroll
    for (int j = 0; j < 8; ++j) {
      float v = src[j];
      unsigned short hb = f2bf(v);
      WhHi[(size_t)tid * 8 + j] = hb;
      WhLo[(size_t)tid * 8 + j] = f2bf(v - bf2f(hb));
    }
  }
}

// ---------------------------------------------------------------------------
// xproj (unchanged)
// ---------------------------------------------------------------------------
__global__ __launch_bounds__(256) void xproj_kernel(const float* __restrict__ x,
    const unsigned short* __restrict__ WxHi, const unsigned short* __restrict__ WxLo,
    const float* __restrict__ bh, float* __restrict__ out) {
  __shared__ unsigned short ahi[128][40];
  __shared__ unsigned short alo[128][40];
  const int tid = threadIdx.x, lane = tid & 63, wid = tid >> 6;
  const int mbase = blockIdx.x * 128, cbase = blockIdx.y * 128;
  const int wrow = (wid >> 1) * 64, wcol = (wid & 1) * 64;
  f32x4 acc[4][4] = {};
  const int srow = tid >> 1, shalf = (tid & 1) * 16;

  for (int kt = 0; kt < 8; ++kt) {
    const f32x4* src = reinterpret_cast<const f32x4*>(
        x + (size_t)(mbase + srow) * I_DIM + kt * 32 + shalf);
    f32x4 v[4];
    v[0] = src[0]; v[1] = src[1]; v[2] = src[2]; v[3] = src[3];
    u16x8 hh[2], ll[2];
    #pragma unroll
    for (int q = 0; q < 2; ++q) {
      #pragma unroll
      for (int e = 0; e < 8; ++e) {
        float f = v[q * 2 + (e >> 2)][e & 3];
        unsigned short hb = f2bf(f);
        hh[q][e] = hb;
        ll[q][e] = f2bf(f - bf2f(hb));
      }
    }
    __syncthreads();
    *reinterpret_cast<u16x8*>(&ahi[srow][shalf]) = hh[0];
    *reinterpret_cast<u16x8*>(&ahi[srow][shalf + 8]) = hh[1];
    *reinterpret_cast<u16x8*>(&alo[srow][shalf]) = ll[0];
    *reinterpret_cast<u16x8*>(&alo[srow][shalf + 8]) = ll[1];
    __syncthreads();

    bf16x8 amh[4], aml[4];
    #pragma unroll
    for (int m = 0; m < 4; ++m) {
      amh[m] = __builtin_bit_cast(bf16x8, *reinterpret_cast<const u16x8*>(
          &ahi[wrow + m * 16 + (lane & 15)][(lane >> 4) * 8]));
      aml[m] = __builtin_bit_cast(bf16x8, *reinterpret_cast<const u16x8*>(
          &alo[wrow + m * 16 + (lane & 15)][(lane >> 4) * 8]));
    }
    bf16x8 bhh[4], bll[4];
    #pragma unroll
    for (int n = 0; n < 4; ++n) {
      int ntg = (cbase + wcol) / 16 + n;
      size_t idx = (size_t)(ntg * 8 + kt) * 64 + lane;
      bhh[n] = ld_frag_g(WxHi, idx);
      bll[n] = ld_frag_g(WxLo, idx);
    }
    #pragma unroll
    for (int m = 0; m < 4; ++m) {
      #pragma unroll
      for (int n = 0; n < 4; ++n) {
        acc[m][n] = __builtin_amdgcn_mfma_f32_16x16x32_bf16(amh[m], bhh[n], acc[m][n], 0, 0, 0);
        acc[m][n] = __builtin_amdgcn_mfma_f32_16x16x32_bf16(aml[m], bhh[n], acc[m][n], 0, 0, 0);
        acc[m][n] = __builtin_amdgcn_mfma_f32_16x16x32_bf16(amh[m], bll[n], acc[m][n], 0, 0, 0);
      }
    }
  }

  #pragma unroll
  for (int n = 0; n < 4; ++n) {
    int col = cbase + wcol + n * 16 + (lane & 15);
    float bv = bh[col];
    #pragma unroll
    for (int m = 0; m < 4; ++m) {
      int rg = mbase + wrow + m * 16 + ((lane >> 4) << 2);
      #pragma unroll
      for (int r = 0; r < 4; ++r)
        out[(size_t)(rg + r) * H_DIM + col] = acc[m][n][r] + bv;
    }
  }
}

// ---------------------------------------------------------------------------
// Recurrence. 64 WGs x 256 thr: g = blk&7 (16 batch rows), c = blk>>3 (64 cols).
// Wh fragments in VGPRs; h_t bf16 in double-buffered LDS. Cross-WG exchange:
// each h element published as u32 = (step<<16) | bf16(h) via relaxed AGENT
// store (4B store = atomic -> data+version arrive together; no tags, no
// fences, no vmcnt drains). Consumers spin on the exact u64 words they
// consume (color check on both u32 halves), strip colors, distribute via
// linear ds_write_b32, one raw s_barrier per step. Deadlock-free: every wave
// publishes before it consumes (forward-only dependence). Cross-replay
// staleness excluded by the 16-bit step color (poison/weight-bits/final
// colors never match first expectations).
// ---------------------------------------------------------------------------
__global__ __launch_bounds__(256, 1) void rnn_kernel(const float* __restrict__ h0,
    const unsigned short* __restrict__ WhHi, const unsigned short* __restrict__ WhLo,
    u32* __restrict__ slab, float* __restrict__ out) {
  __shared__ __attribute__((aligned(16))) unsigned short hb[2][16 * 520];
  const int tid = threadIdx.x, lane = tid & 63, w = tid >> 6;
  const int g = blockIdx.x & 7, c = blockIdx.x >> 3;

  // ---- one-time: Wh fragments -> VGPRs ----
  bf16x8 wfh[16], wfl[16];
  #pragma unroll
  for (int kt = 0; kt < 16; ++kt) {
    size_t idx = (size_t)((c * 4 + w) * 16 + kt) * 64 + lane;
    wfh[kt] = ld_frag_g(WhHi, idx);
    wfl[kt] = ld_frag_g(WhLo, idx);
  }
  // ---- one-time: h0 -> LDS bf16 (buffer 0) ----
  for (int i = tid; i < 1024; i += 256) {
    int row = i >> 6, col0 = (i & 63) * 8;
    const f32x4* s = reinterpret_cast<const f32x4*>(h0 + (size_t)(g * 16 + row) * H_DIM + col0);
    f32x4 v0 = s[0], v1 = s[1];
    u16x8 hv;
    #pragma unroll
    for (int e = 0; e < 4; ++e) { hv[e] = f2bf(v0[e]); hv[4 + e] = f2bf(v1[e]); }
    *reinterpret_cast<u16x8*>(&hb[0][row * 520 + col0]) = hv;
  }
  __syncthreads();

  const int arow = lane & 15;        // A row (batch); also D col
  const int aoff = (lane >> 4) * 8;  // A k offset
  const int drow = (lane >> 4) * 4;  // D row base
  const int gcol = c * 64 + w * 16 + (lane & 15);

  // xp prefetch for t=0
  f32x4 xpv;
  #pragma unroll
  for (int r = 0; r < 4; ++r)
    xpv[r] = out[(size_t)(g * 16 + drow + r) * H_DIM + gcol];

  for (int t = 0; t < L_DIM; ++t) {
    const size_t obase = ((size_t)t * B_DIM + g * 16) * H_DIM;
    const unsigned short* hbc = hb[t & 1];

    // ---- z = h_t . Wh (hi+lo), 32 MFMAs, 4 chains ----
    bf16x8 af[16];
    #pragma unroll
    for (int kt = 0; kt < 16; ++kt)
      af[kt] = __builtin_bit_cast(bf16x8, *reinterpret_cast<const u16x8*>(
          &hbc[arow * 520 + kt * 32 + aoff]));
    f32x4 a0 = {}, a1 = {}, a2 = {}, a3 = {};
    #pragma unroll
    for (int kt = 0; kt < 16; kt += 2) {
      a0 = __builtin_amdgcn_mfma_f32_16x16x32_bf16(af[kt], wfh[kt], a0, 0, 0, 0);
      a1 = __builtin_amdgcn_mfma_f32_16x16x32_bf16(af[kt], wfl[kt], a1, 0, 0, 0);
      a2 = __builtin_amdgcn_mfma_f32_16x16x32_bf16(af[kt + 1], wfh[kt + 1], a2, 0, 0, 0);
      a3 = __builtin_amdgcn_mfma_f32_16x16x32_bf16(af[kt + 1], wfl[kt + 1], a3, 0, 0, 0);
    }

    float hv[4]; unsigned short hu[4];
    #pragma unroll
    for (int r = 0; r < 4; ++r) {
      float z = a0[r] + a1[r] + a2[r] + a3[r] + xpv[r];
      float e = __expf(2.0f * z);
      hv[r] = 1.0f - 2.0f / (e + 1.0f);  // tanh(z)
      hu[r] = f2bf(hv[r]);
    }

    if (t < L_DIM - 1) {
      const unsigned step = (unsigned)(t + 1);
      u32* sg = slab + ((size_t)((step & 1) * 8 + g)) * 8192;  // [16][512] u32
      const unsigned cbits = step << 16;

      // ---- publish own 16x64 tile: 4 color-stamped u32 stores (atomic 4B) ----
      #pragma unroll
      for (int r = 0; r < 4; ++r)
        __hip_atomic_store(&sg[(drow + r) * 512 + gcol], cbits | (u32)hu[r],
                           __ATOMIC_RELAXED, __HIP_MEMORY_SCOPE_AGENT);

      // ---- off-critical-path: out stores + xp(t+1) loads (fly during spin) ----
      #pragma unroll
      for (int r = 0; r < 4; ++r)
        out[obase + (size_t)(drow + r) * H_DIM + gcol] = hv[r];
      const size_t obn = ((size_t)(t + 1) * B_DIM + g * 16) * H_DIM;
      #pragma unroll
      for (int r = 0; r < 4; ++r)
        xpv[r] = out[obn + (size_t)(drow + r) * H_DIM + gcol];

      // ---- pull h_{t+1}: thread owns column-pair tid across all 16 rows ----
      u64* sp = reinterpret_cast<u64*>(sg);
      u64 pv[16];
      #pragma unroll
      for (int row = 0; row < 16; ++row)
        pv[row] = __hip_atomic_load(sp + row * 256 + tid,
                                    __ATOMIC_RELAXED, __HIP_MEMORY_SCOPE_AGENT);
      const u64 expect = (u64)step * 0x0001000000010000ull;
      #pragma unroll
      for (int row = 0; row < 16; ++row) {
        while ((pv[row] & 0xFFFF0000FFFF0000ull) != expect)
          pv[row] = __hip_atomic_load(sp + row * 256 + tid,
                                      __ATOMIC_RELAXED, __HIP_MEMORY_SCOPE_AGENT);
      }

      // ---- strip colors, distribute into the other LDS buffer (linear b32) ----
      unsigned short* hbn = hb[(t + 1) & 1];
      #pragma unroll
      for (int row = 0; row < 16; ++row) {
        u32 pk = (u32)(pv[row] & 0xFFFFull) | (u32)((pv[row] >> 16) & 0xFFFF0000ull);
        *reinterpret_cast<u32*>(&hbn[row * 520 + 2 * tid]) = pk;
      }
      __builtin_amdgcn_sched_barrier(0);
      asm volatile("s_waitcnt lgkmcnt(0)" ::: "memory");
      __builtin_amdgcn_sched_barrier(0);
      __builtin_amdgcn_s_barrier();      // hb[(t+1)&1] = h_{t+1} WG-wide
      __builtin_amdgcn_sched_barrier(0);
    } else {
      #pragma unroll
      for (int r = 0; r < 4; ++r)
        out[obase + (size_t)(drow + r) * H_DIM + gcol] = hv[r];
    }
  }
}

extern "C" void kernel_launch(void* const* d_in, const int* in_sizes, int n_in,
                              void* d_out, int out_size, void* d_ws, size_t ws_size,
                              hipStream_t stream) {
  (void)in_sizes; (void)n_in; (void)out_size; (void)ws_size;
  const float* x  = (const float*)d_in[0];
  const float* h0 = (const float*)d_in[1];
  const float* Wx = (const float*)d_in[2];
  const float* Wh = (const float*)d_in[3];
  const float* bh = (const float*)d_in[4];
  float* out = (float*)d_out;

  unsigned short* WxHi = (unsigned short*)d_ws;       // 131072 u16 (dead after xproj)
  unsigned short* WxLo = WxHi + 131072;               // 131072 u16 (dead after xproj)
  unsigned short* WhHi = WxLo + 131072;               // 262144 u16
  unsigned short* WhLo = WhHi + 262144;               // 262144 u16 (ends 1572864 B)
  // slab aliases the Wx pack region (512 KB, unused once xproj completes).
  // Stale color check vs Wx bf16 bits: colors 1..1024 are denormal bit
  // patterns that the uniform RNG weights never produce; first expected
  // colors per slab are 1 and 2.
  u32* slab = (u32*)d_ws;                              // 2*8*8192 u32 = 524288 B

  hipLaunchKernelGGL(pack_weights, dim3(128), dim3(256), 0, stream,
                     Wx, Wh, WxHi, WxLo, WhHi, WhLo);
  hipLaunchKernelGGL(xproj_kernel, dim3(1024, 4), dim3(256), 0, stream,
                     x, WxHi, WxLo, bh, out);
  hipLaunchKernelGGL(rnn_kernel, dim3(64), dim3(256), 0, stream,
                     h0, WhHi, WhLo, slab, out);
}

// Round 7
// 3219.880 us; speedup vs baseline: 1.2858x; 1.2858x over previous
//
#include <hip/hip_runtime.h>

#define L_DIM 1024
#define B_DIM 128
#define I_DIM 256
#define H_DIM 512

typedef unsigned short u16x8 __attribute__((ext_vector_type(8)));
typedef __bf16 bf16x8 __attribute__((ext_vector_type(8)));
typedef float f32x4 __attribute__((ext_vector_type(4)));
typedef unsigned long long u64;
typedef unsigned int u32;
typedef u64 u64x2 __attribute__((ext_vector_type(2)));

static __device__ __forceinline__ unsigned short f2bf(float f) {
  unsigned u = __builtin_bit_cast(unsigned, f);
  u += 0x7FFFu + ((u >> 16) & 1u);
  return (unsigned short)(u >> 16);
}
static __device__ __forceinline__ float bf2f(unsigned short b) {
  return __builtin_bit_cast(float, ((unsigned)b) << 16);
}
static __device__ __forceinline__ bf16x8 ld_frag_g(const unsigned short* p, size_t idx8) {
  return __builtin_bit_cast(bf16x8, reinterpret_cast<const u16x8*>(p)[idx8]);
}

// ---------------------------------------------------------------------------
// Pack Wx and Wh into MFMA B-fragment order, split hi/lo bf16. (unchanged)
// B-frag: lane l holds B[k = kt*32+(l>>4)*8+j][n = nt*16+(l&15)], W stored [n][k].
// ---------------------------------------------------------------------------
__global__ void pack_weights(const float* __restrict__ Wx, const float* __restrict__ Wh,
                             unsigned short* __restrict__ WxHi, unsigned short* __restrict__ WxLo,
                             unsigned short* __restrict__ WhHi, unsigned short* __restrict__ WhLo) {
  int tid = blockIdx.x * blockDim.x + threadIdx.x;
  if (tid < 32 * 8 * 64) {
    int lane = tid & 63, kt = (tid >> 6) & 7, nt = tid >> 9;
    int n = nt * 16 + (lane & 15), k0 = kt * 32 + (lane >> 4) * 8;
    const float* src = Wx + (size_t)n * I_DIM + k0;
    #pragma unroll
    for (int j = 0; j < 8; ++j) {
      float v = src[j];
      unsigned short hb = f2bf(v);
      WxHi[(size_t)tid * 8 + j] = hb;
      WxLo[(size_t)tid * 8 + j] = f2bf(v - bf2f(hb));
    }
  }
  if (tid < 32 * 16 * 64) {
    int lane = tid & 63, kt = (tid >> 6) & 15, nt = tid >> 10;
    int n = nt * 16 + (lane & 15), k0 = kt * 32 + (lane >> 4) * 8;
    const float* src = Wh + (size_t)n * H_DIM + k0;
    #pragma unroll
    for (int j = 0; j < 8; ++j) {
      float v = src[j];
      unsigned short hb = f2bf(v);
      WhHi[(size_t)tid * 8 + j] = hb;
      WhLo[(size_t)tid * 8 + j] = f2bf(v - bf2f(hb));
    }
  }
}

// ---------------------------------------------------------------------------
// xproj (unchanged)
// ---------------------------------------------------------------------------
__global__ __launch_bounds__(256) void xproj_kernel(const float* __restrict__ x,
    const unsigned short* __restrict__ WxHi, const unsigned short* __restrict__ WxLo,
    const float* __restrict__ bh, float* __restrict__ out) {
  __shared__ unsigned short ahi[128][40];
  __shared__ unsigned short alo[128][40];
  const int tid = threadIdx.x, lane = tid & 63, wid = tid >> 6;
  const int mbase = blockIdx.x * 128, cbase = blockIdx.y * 128;
  const int wrow = (wid >> 1) * 64, wcol = (wid & 1) * 64;
  f32x4 acc[4][4] = {};
  const int srow = tid >> 1, shalf = (tid & 1) * 16;

  for (int kt = 0; kt < 8; ++kt) {
    const f32x4* src = reinterpret_cast<const f32x4*>(
        x + (size_t)(mbase + srow) * I_DIM + kt * 32 + shalf);
    f32x4 v[4];
    v[0] = src[0]; v[1] = src[1]; v[2] = src[2]; v[3] = src[3];
    u16x8 hh[2], ll[2];
    #pragma unroll
    for (int q = 0; q < 2; ++q) {
      #pragma unroll
      for (int e = 0; e < 8; ++e) {
        float f = v[q * 2 + (e >> 2)][e & 3];
        unsigned short hb = f2bf(f);
        hh[q][e] = hb;
        ll[q][e] = f2bf(f - bf2f(hb));
      }
    }
    __syncthreads();
    *reinterpret_cast<u16x8*>(&ahi[srow][shalf]) = hh[0];
    *reinterpret_cast<u16x8*>(&ahi[srow][shalf + 8]) = hh[1];
    *reinterpret_cast<u16x8*>(&alo[srow][shalf]) = ll[0];
    *reinterpret_cast<u16x8*>(&alo[srow][shalf + 8]) = ll[1];
    __syncthreads();

    bf16x8 amh[4], aml[4];
    #pragma unroll
    for (int m = 0; m < 4; ++m) {
      amh[m] = __builtin_bit_cast(bf16x8, *reinterpret_cast<const u16x8*>(
          &ahi[wrow + m * 16 + (lane & 15)][(lane >> 4) * 8]));
      aml[m] = __builtin_bit_cast(bf16x8, *reinterpret_cast<const u16x8*>(
          &alo[wrow + m * 16 + (lane & 15)][(lane >> 4) * 8]));
    }
    bf16x8 bhh[4], bll[4];
    #pragma unroll
    for (int n = 0; n < 4; ++n) {
      int ntg = (cbase + wcol) / 16 + n;
      size_t idx = (size_t)(ntg * 8 + kt) * 64 + lane;
      bhh[n] = ld_frag_g(WxHi, idx);
      bll[n] = ld_frag_g(WxLo, idx);
    }
    #pragma unroll
    for (int m = 0; m < 4; ++m) {
      #pragma unroll
      for (int n = 0; n < 4; ++n) {
        acc[m][n] = __builtin_amdgcn_mfma_f32_16x16x32_bf16(amh[m], bhh[n], acc[m][n], 0, 0, 0);
        acc[m][n] = __builtin_amdgcn_mfma_f32_16x16x32_bf16(aml[m], bhh[n], acc[m][n], 0, 0, 0);
        acc[m][n] = __builtin_amdgcn_mfma_f32_16x16x32_bf16(amh[m], bll[n], acc[m][n], 0, 0, 0);
      }
    }
  }

  #pragma unroll
  for (int n = 0; n < 4; ++n) {
    int col = cbase + wcol + n * 16 + (lane & 15);
    float bv = bh[col];
    #pragma unroll
    for (int m = 0; m < 4; ++m) {
      int rg = mbase + wrow + m * 16 + ((lane >> 4) << 2);
      #pragma unroll
      for (int r = 0; r < 4; ++r)
        out[(size_t)(rg + r) * H_DIM + col] = acc[m][n][r] + bv;
    }
  }
}

// ---------------------------------------------------------------------------
// Recurrence: 256 single-wave WGs (64 thr). Block b -> g=b&7 (16 batch rows),
// c=(b>>3)&7, w=(b>>6)&3: wave owns output cols c*64+w*16 .. +15. Wh hi/lo
// fragments in 128 VGPRs. NO LDS, NO barriers. Per step:
//   publish own 16(rows)x16(cols) bf16 tile (4x 2B agent stores) ->
//   vmcnt(0) -> per-wave tag; out stores + xp(t+1) prefetch fly during poll;
//   lanes 0..31 poll the group's 32 per-wave tags; then each lane pulls its
//   16 MFMA A-fragments (8 contiguous bf16 = 2 u64 agent loads) directly
//   from the row-major slab [buf][g][16][512]. Pull-once-fresh (R4-proven
//   tag ordering); double-buffered slab, max inter-wave skew = 1 step.
// ---------------------------------------------------------------------------
__global__ __launch_bounds__(64, 1) void rnn_kernel(const float* __restrict__ h0,
    const unsigned short* __restrict__ WhHi, const unsigned short* __restrict__ WhLo,
    u32* __restrict__ tags, unsigned short* __restrict__ slab,
    float* __restrict__ out) {
  const int lane = threadIdx.x & 63;
  const int b = blockIdx.x;
  const int g = b & 7, c = (b >> 3) & 7, w = (b >> 6) & 3;
  const int cw = c * 4 + w;  // producer-wave index within group (0..31)

  // ---- one-time: Wh fragments -> VGPRs (16 cols x 512 k, hi+lo) ----
  bf16x8 wfh[16], wfl[16];
  #pragma unroll
  for (int kt = 0; kt < 16; ++kt) {
    size_t idx = (size_t)(cw * 16 + kt) * 64 + lane;
    wfh[kt] = ld_frag_g(WhHi, idx);
    wfl[kt] = ld_frag_g(WhLo, idx);
  }

  const int arow = lane & 15;        // A row (batch); D col within 16
  const int aoff = (lane >> 4) * 8;  // A k offset
  const int drow = (lane >> 4) * 4;  // D row base
  const int gcol = c * 64 + w * 16 + (lane & 15);
  const int koff2 = (lane >> 4) * 2; // u64 offset of A-frag within 32-col ktile

  // ---- one-time: h_0 A-fragments straight from h0 (fp32 -> bf16) ----
  bf16x8 af[16];
  #pragma unroll
  for (int kt = 0; kt < 16; ++kt) {
    const f32x4* hp = reinterpret_cast<const f32x4*>(
        h0 + (size_t)(g * 16 + arow) * H_DIM + kt * 32 + aoff);
    f32x4 v0 = hp[0], v1 = hp[1];
    u16x8 hv;
    #pragma unroll
    for (int e = 0; e < 4; ++e) { hv[e] = f2bf(v0[e]); hv[4 + e] = f2bf(v1[e]); }
    af[kt] = __builtin_bit_cast(bf16x8, hv);
  }

  // xp prefetch for t=0
  f32x4 xpv;
  #pragma unroll
  for (int r = 0; r < 4; ++r)
    xpv[r] = out[(size_t)(g * 16 + drow + r) * H_DIM + gcol];

  for (int t = 0; t < L_DIM; ++t) {
    const size_t obase = ((size_t)t * B_DIM + g * 16) * H_DIM;

    // ---- z = h_t . Wh (hi+lo): 32 MFMAs, 4 chains ----
    f32x4 a0 = {}, a1 = {}, a2 = {}, a3 = {};
    #pragma unroll
    for (int kt = 0; kt < 16; kt += 2) {
      a0 = __builtin_amdgcn_mfma_f32_16x16x32_bf16(af[kt], wfh[kt], a0, 0, 0, 0);
      a1 = __builtin_amdgcn_mfma_f32_16x16x32_bf16(af[kt], wfl[kt], a1, 0, 0, 0);
      a2 = __builtin_amdgcn_mfma_f32_16x16x32_bf16(af[kt + 1], wfh[kt + 1], a2, 0, 0, 0);
      a3 = __builtin_amdgcn_mfma_f32_16x16x32_bf16(af[kt + 1], wfl[kt + 1], a3, 0, 0, 0);
    }

    float hv[4]; unsigned short hu[4];
    #pragma unroll
    for (int r = 0; r < 4; ++r) {
      float z = a0[r] + a1[r] + a2[r] + a3[r] + xpv[r];
      float e = __expf(2.0f * z);
      hv[r] = 1.0f - 2.0f / (e + 1.0f);  // tanh(z)
      hu[r] = f2bf(hv[r]);
    }

    if (t < L_DIM - 1) {
      const unsigned step = (unsigned)(t + 1);
      const unsigned buf = step & 1;
      unsigned short* sg = slab + (size_t)(buf * 8 + g) * 8192;  // [16][512] bf16

      // ---- publish own tile: 4x 2B agent stores ----
      #pragma unroll
      for (int r = 0; r < 4; ++r)
        __hip_atomic_store(&sg[(drow + r) * H_DIM + gcol], hu[r],
                           __ATOMIC_RELAXED, __HIP_MEMORY_SCOPE_AGENT);
      __builtin_amdgcn_sched_barrier(0);
      asm volatile("s_waitcnt vmcnt(0)" ::: "memory");  // tile at coherent point
      __builtin_amdgcn_sched_barrier(0);
      if (lane == 0)
        __hip_atomic_store(tags + ((size_t)(buf * 8 + g) * 32 + cw) * 16, step,
                           __ATOMIC_RELAXED, __HIP_MEMORY_SCOPE_AGENT);

      // ---- off-critical-path: out stores + xp(t+1) loads (fly during poll) ----
      #pragma unroll
      for (int r = 0; r < 4; ++r)
        out[obase + (size_t)(drow + r) * H_DIM + gcol] = hv[r];
      const size_t obn = ((size_t)(t + 1) * B_DIM + g * 16) * H_DIM;
      #pragma unroll
      for (int r = 0; r < 4; ++r)
        xpv[r] = out[obn + (size_t)(drow + r) * H_DIM + gcol];

      // ---- poll all 32 per-wave tags of the group (lanes 0..31) ----
      if (lane < 32) {
        const u32* tp = tags + ((size_t)(buf * 8 + g) * 32 + lane) * 16;
        while (__hip_atomic_load(tp, __ATOMIC_RELAXED, __HIP_MEMORY_SCOPE_AGENT) < step) {}
      }
      __builtin_amdgcn_sched_barrier(0);
      asm volatile("" ::: "memory");

      // ---- pull h_{t+1} A-fragments directly (2 u64 agent loads per ktile) ----
      const u64* sp = reinterpret_cast<const u64*>(sg);
      #pragma unroll
      for (int kt = 0; kt < 16; ++kt) {
        const u64* p = sp + arow * 128 + kt * 8 + koff2;
        u64x2 pv;
        pv[0] = __hip_atomic_load(p, __ATOMIC_RELAXED, __HIP_MEMORY_SCOPE_AGENT);
        pv[1] = __hip_atomic_load(p + 1, __ATOMIC_RELAXED, __HIP_MEMORY_SCOPE_AGENT);
        af[kt] = __builtin_bit_cast(bf16x8, pv);
      }
    } else {
      #pragma unroll
      for (int r = 0; r < 4; ++r)
        out[obase + (size_t)(drow + r) * H_DIM + gcol] = hv[r];
    }
  }
}

extern "C" void kernel_launch(void* const* d_in, const int* in_sizes, int n_in,
                              void* d_out, int out_size, void* d_ws, size_t ws_size,
                              hipStream_t stream) {
  (void)in_sizes; (void)n_in; (void)out_size; (void)ws_size;
  const float* x  = (const float*)d_in[0];
  const float* h0 = (const float*)d_in[1];
  const float* Wx = (const float*)d_in[2];
  const float* Wh = (const float*)d_in[3];
  const float* bh = (const float*)d_in[4];
  float* out = (float*)d_out;

  unsigned short* WxHi = (unsigned short*)d_ws;       // 131072 u16
  unsigned short* WxLo = WxHi + 131072;               // 131072 u16
  unsigned short* WhHi = WxLo + 131072;               // 262144 u16
  unsigned short* WhLo = WhHi + 262144;               // 262144 u16 (ends 1572864 B)
  unsigned short* slab = (unsigned short*)((char*)d_ws + 1572864);  // [2][8][16][512] bf16 = 262144 B
  u32*            tags = (u32*)((char*)d_ws + 1835008);             // 2*8*32 tags x 64B = 32768 B

  // per-launch: zero tags (deterministic under graph replay)
  hipMemsetAsync(tags, 0, 32768, stream);

  hipLaunchKernelGGL(pack_weights, dim3(128), dim3(256), 0, stream,
                     Wx, Wh, WxHi, WxLo, WhHi, WhLo);
  hipLaunchKernelGGL(xproj_kernel, dim3(1024, 4), dim3(256), 0, stream,
                     x, WxHi, WxLo, bh, out);
  hipLaunchKernelGGL(rnn_kernel, dim3(256), dim3(64), 0, stream,
                     h0, WhHi, WhLo, tags, slab, out);
}